// Round 2
// baseline (285.871 us; speedup 1.0000x reference)
//
#include <hip/hip_runtime.h>
#include <math.h>

// IDCT2 (DCT-III, ortho) over (16,32,256,256) fp32 via bf16 MFMA.
// Z = M * X * M^T, M[n][k] = w[k]*cos(pi*k*(2n+1)/512).
//
// Round-2 fused kernel: one block per HALF-batch (n-slice of 128).
//   Stage 1: W^T[n][i] = sum_k X[i][k] M[n][k], n in slice -> bf16 LDS (swizzled)
//   Stage 2: Z[m][n]   = sum_i M[m][i] W[i][n], n in slice -> direct fp32 stores
// LDS: union{ Xs double-buffer 2x20.5 KB (k-loop only) ; Wt 128x512B (epilogue
// + stage2 only) } = 64 KB static -> 2 blocks/CU, 16 waves/CU.
// Block swizzle pairs the two halves of a batch on one XCD (shared X in L2).

constexpr int N = 256;
typedef __attribute__((ext_vector_type(8))) short short8;
typedef __attribute__((ext_vector_type(4))) float f32x4;

constexpr int XS_STRIDE = 40;                 // ushorts per row (2-way bank alias: free)
constexpr int XS_TILE   = 256 * XS_STRIDE;    // ushorts per buffer (20480 B)

__device__ __forceinline__ unsigned short f2bf(float f) {
    unsigned int u = __float_as_uint(f);
    u += 0x7fffu + ((u >> 16) & 1u);
    return (unsigned short)(u >> 16);
}

__device__ __forceinline__ float mvalf(int n, int k) {
    const float CST = 0.006135923151542565f;  // pi/512
    const float W0  = 0.0625f;                // 1/sqrt(256)
    const float WK  = 0.08838834764831845f;   // sqrt(2/256)
    int q = (k * (2 * n + 1)) & 1023;
    return ((k == 0) ? W0 : WK) * __cosf(CST * (float)q);
}

__global__ __launch_bounds__(256) void mgen(unsigned short* __restrict__ Mg) {
    int idx = blockIdx.x * 256 + threadIdx.x;
    int n = idx >> 8, k = idx & 255;
    Mg[idx] = f2bf(mvalf(n, k));
}

__global__ __launch_bounds__(512, 4) void idct_fused2(
        const float* __restrict__ X,
        const unsigned short* __restrict__ Mg,
        float* __restrict__ Z) {
    __shared__ __align__(16) unsigned char smem[65536];
    unsigned short* Xs0 = (unsigned short*)smem;            // [256][40] bf16
    unsigned short* Xs1 = Xs0 + XS_TILE;                    // second buffer
    // Wt: 128 rows x 512 B (bf16, XOR-swizzled), union'd over the whole smem.

    // Bijective XCD-chunked swizzle: consecutive sw (= same batch's two
    // halves) come from bids 8 apart -> same XCD under round-robin dispatch.
    const int bid = blockIdx.x, nb = gridDim.x;
    const int sw = ((nb & 7) == 0) ? ((bid & 7) * (nb >> 3) + (bid >> 3)) : bid;
    const int batch = sw >> 1;
    const int n0 = (sw & 1) << 7;               // n-slice base: 0 or 128

    const float* Xb = X + (size_t)batch * N * N;
    float*       Zb = Z + (size_t)batch * N * N;

    const int tid = threadIdx.x;
    const int w  = tid >> 6, l = tid & 63;
    const int q  = l >> 4, lr = l & 15;
    const int wi = w >> 1;                      // i-tile (stage1) / m-tile (stage2), 0..3
    const int wn = w & 1;                       // n-tile, 0..1
    const int srow = tid >> 1, sh = tid & 1;    // staging: row, 16-col half

    const float* xsrc = Xb + (size_t)srow * N + sh * 16;
    const int xoff = srow * XS_STRIDE + sh * 16;

    // Stage-1 M row base pointers (n rows of this slice), loop-invariant.
    const unsigned short* mrow0 = Mg + (n0 + wn * 64 +  0 + lr) * N;
    const unsigned short* mrow1 = Mg + (n0 + wn * 64 + 16 + lr) * N;
    const unsigned short* mrow2 = Mg + (n0 + wn * 64 + 32 + lr) * N;
    const unsigned short* mrow3 = Mg + (n0 + wn * 64 + 48 + lr) * N;

    f32x4 acc[4][4];
    #pragma unroll
    for (int r = 0; r < 4; ++r)
        #pragma unroll
        for (int c = 0; c < 4; ++c) acc[r][c] = f32x4{0.f, 0.f, 0.f, 0.f};

    // ---------------- Stage 1: W^T (n-slice) into LDS ----------------
    float4 u0, u1, u2, u3;
    {   // tile 0 load + store to Xs0
        const float4* p = (const float4*)xsrc;
        u0 = p[0]; u1 = p[1]; u2 = p[2]; u3 = p[3];
        ushort4 p0 = {f2bf(u0.x), f2bf(u0.y), f2bf(u0.z), f2bf(u0.w)};
        ushort4 p1 = {f2bf(u1.x), f2bf(u1.y), f2bf(u1.z), f2bf(u1.w)};
        ushort4 p2 = {f2bf(u2.x), f2bf(u2.y), f2bf(u2.z), f2bf(u2.w)};
        ushort4 p3 = {f2bf(u3.x), f2bf(u3.y), f2bf(u3.z), f2bf(u3.w)};
        *(ushort4*)&Xs0[xoff + 0]  = p0;
        *(ushort4*)&Xs0[xoff + 4]  = p1;
        *(ushort4*)&Xs0[xoff + 8]  = p2;
        *(ushort4*)&Xs0[xoff + 12] = p3;
    }
    {   // tile 1 prefetch
        const float4* p = (const float4*)(xsrc + 32);
        u0 = p[0]; u1 = p[1]; u2 = p[2]; u3 = p[3];
    }
    __syncthreads();

    #pragma unroll
    for (int kt = 0; kt < 8; ++kt) {
        unsigned short* xcur = (kt & 1) ? Xs1 : Xs0;
        unsigned short* xnxt = (kt & 1) ? Xs0 : Xs1;

        short8 afr[4], bfr[4];
        #pragma unroll
        for (int r = 0; r < 4; ++r)
            afr[r] = *(const short8*)&xcur[(wi * 64 + r * 16 + lr) * XS_STRIDE + q * 8];
        bfr[0] = *(const short8*)(mrow0 + kt * 32 + q * 8);
        bfr[1] = *(const short8*)(mrow1 + kt * 32 + q * 8);
        bfr[2] = *(const short8*)(mrow2 + kt * 32 + q * 8);
        bfr[3] = *(const short8*)(mrow3 + kt * 32 + q * 8);

        if (kt < 7) {   // write tile kt+1 (held in u) to the other buffer
            ushort4 p0 = {f2bf(u0.x), f2bf(u0.y), f2bf(u0.z), f2bf(u0.w)};
            ushort4 p1 = {f2bf(u1.x), f2bf(u1.y), f2bf(u1.z), f2bf(u1.w)};
            ushort4 p2 = {f2bf(u2.x), f2bf(u2.y), f2bf(u2.z), f2bf(u2.w)};
            ushort4 p3 = {f2bf(u3.x), f2bf(u3.y), f2bf(u3.z), f2bf(u3.w)};
            *(ushort4*)&xnxt[xoff + 0]  = p0;
            *(ushort4*)&xnxt[xoff + 4]  = p1;
            *(ushort4*)&xnxt[xoff + 8]  = p2;
            *(ushort4*)&xnxt[xoff + 12] = p3;
        }
        if (kt < 6) {   // prefetch tile kt+2
            const float4* p = (const float4*)(xsrc + (kt + 2) * 32);
            u0 = p[0]; u1 = p[1]; u2 = p[2]; u3 = p[3];
        }

        __builtin_amdgcn_s_setprio(1);
        #pragma unroll
        for (int r = 0; r < 4; ++r)
            #pragma unroll
            for (int c = 0; c < 4; ++c)
                acc[r][c] = __builtin_amdgcn_mfma_f32_16x16x32_bf16(
                    afr[r], bfr[c], acc[r][c], 0, 0, 0);
        __builtin_amdgcn_s_setprio(0);
        __syncthreads();
    }

    // Epilogue: acc[r][c][j] = W[i = wi*64+r*16+q*4+j][n = n0+wn*64+c*16+lr].
    // Write W^T bf16 into smem (overlaps Xs — safe: final k-loop barrier done).
    #pragma unroll
    for (int r = 0; r < 4; ++r)
        #pragma unroll
        for (int c = 0; c < 4; ++c) {
            ushort4 pw = {f2bf(acc[r][c][0]), f2bf(acc[r][c][1]),
                          f2bf(acc[r][c][2]), f2bf(acc[r][c][3])};
            int nloc = wn * 64 + c * 16 + lr;
            int i2   = (wi * 64 + r * 16 + q * 4) * 2;
            *(ushort4*)(smem + nloc * 512 + (i2 ^ ((nloc & 7) << 4))) = pw;
        }
    __syncthreads();

    // ---------------- Stage 2: Z[:, n-slice] = M * W (barrier-free) --------
    f32x4 acc2[4][4];
    #pragma unroll
    for (int r = 0; r < 4; ++r)
        #pragma unroll
        for (int c = 0; c < 4; ++c) acc2[r][c] = f32x4{0.f, 0.f, 0.f, 0.f};

    const unsigned short* m2row0 = Mg + (wi * 64 +  0 + lr) * N;
    const unsigned short* m2row1 = Mg + (wi * 64 + 16 + lr) * N;
    const unsigned short* m2row2 = Mg + (wi * 64 + 32 + lr) * N;
    const unsigned short* m2row3 = Mg + (wi * 64 + 48 + lr) * N;
    int arow[4], aswz[4];
    #pragma unroll
    for (int r = 0; r < 4; ++r) {
        int nloc = wn * 64 + r * 16 + lr;
        arow[r] = nloc * 512;
        aswz[r] = (nloc & 7) << 4;
    }

    #pragma unroll 2
    for (int it = 0; it < 8; ++it) {
        const int i0 = it * 32;
        short8 af[4], bf[4];
        bf[0] = *(const short8*)(m2row0 + i0 + q * 8);
        bf[1] = *(const short8*)(m2row1 + i0 + q * 8);
        bf[2] = *(const short8*)(m2row2 + i0 + q * 8);
        bf[3] = *(const short8*)(m2row3 + i0 + q * 8);
        #pragma unroll
        for (int r = 0; r < 4; ++r)
            af[r] = *(const short8*)(smem + arow[r] + (((i0 + q * 8) * 2) ^ aswz[r]));
        __builtin_amdgcn_s_setprio(1);
        #pragma unroll
        for (int r = 0; r < 4; ++r)
            #pragma unroll
            for (int c = 0; c < 4; ++c)
                acc2[r][c] = __builtin_amdgcn_mfma_f32_16x16x32_bf16(
                    af[r], bf[c], acc2[r][c], 0, 0, 0);
        __builtin_amdgcn_s_setprio(0);
    }

    // acc2[r][c][j] = Z[m = wi*64+c*16+lr][n = n0+wn*64+r*16+q*4+j]
    #pragma unroll
    for (int r = 0; r < 4; ++r)
        #pragma unroll
        for (int c = 0; c < 4; ++c) {
            float4 v = make_float4(acc2[r][c][0], acc2[r][c][1],
                                   acc2[r][c][2], acc2[r][c][3]);
            int m  = wi * 64 + c * 16 + lr;
            int nn = n0 + wn * 64 + r * 16 + q * 4;
            *(float4*)(Zb + (size_t)m * N + nn) = v;
        }
}

// ================= fp32 fallback (ws too small) — round-1 kernels =========
__global__ __launch_bounds__(256) void idct_cols(const float* __restrict__ X,
                                                 float* __restrict__ Y) {
    const int n0 = blockIdx.x * 64;
    const int i0 = blockIdx.y * 64;
    const float* Xb = X + (size_t)blockIdx.z * N * N;
    float* Yb = Y + (size_t)blockIdx.z * N * N;
    __shared__ float Ast[16][68];
    __shared__ float Bs[16][68];
    const int tid = threadIdx.x;
    const int tx = tid & 15, ty = tid >> 4;
    float acc[4][4] = {};
    for (int k0 = 0; k0 < N; k0 += 16) {
        {
            int r = tid >> 2, c4 = (tid & 3) << 2;
            float4 v = *reinterpret_cast<const float4*>(Xb + (size_t)(i0 + r) * N + k0 + c4);
            Ast[c4 + 0][r] = v.x; Ast[c4 + 1][r] = v.y;
            Ast[c4 + 2][r] = v.z; Ast[c4 + 3][r] = v.w;
        }
        #pragma unroll
        for (int j = 0; j < 4; ++j) {
            int ll = tid + 256 * j;
            Bs[ll >> 6][ll & 63] = mvalf(n0 + (ll & 63), k0 + (ll >> 6));
        }
        __syncthreads();
        #pragma unroll
        for (int kk = 0; kk < 16; ++kk) {
            float4 av = *reinterpret_cast<const float4*>(&Ast[kk][ty << 2]);
            float4 bv = *reinterpret_cast<const float4*>(&Bs[kk][tx << 2]);
            float a[4] = {av.x, av.y, av.z, av.w};
            float bb[4] = {bv.x, bv.y, bv.z, bv.w};
            #pragma unroll
            for (int r = 0; r < 4; ++r)
                #pragma unroll
                for (int c = 0; c < 4; ++c) acc[r][c] += a[r] * bb[c];
        }
        __syncthreads();
    }
    #pragma unroll
    for (int r = 0; r < 4; ++r) {
        float4 v = make_float4(acc[r][0], acc[r][1], acc[r][2], acc[r][3]);
        *reinterpret_cast<float4*>(Yb + (size_t)(i0 + (ty << 2) + r) * N + n0 + (tx << 2)) = v;
    }
}

__global__ __launch_bounds__(512) void idct_rows_inplace(float* __restrict__ Y) {
    const int n0 = blockIdx.x * 64;
    float* Yb = Y + (size_t)blockIdx.y * N * N;
    __shared__ float Ys[256][68];
    __shared__ float Ms[16][256];
    const int tid = threadIdx.x;
    #pragma unroll
    for (int j = 0; j < 8; ++j) {
        int ll = tid + 512 * j;
        int row = ll >> 4, c4 = (ll & 15) << 2;
        *reinterpret_cast<float4*>(&Ys[row][c4]) =
            *reinterpret_cast<const float4*>(Yb + (size_t)row * N + n0 + c4);
    }
    __syncthreads();
    const int tx = tid & 15, ty = tid >> 4;
    float acc[8][4] = {};
    for (int i0 = 0; i0 < N; i0 += 16) {
        __syncthreads();
        #pragma unroll
        for (int j = 0; j < 8; ++j) {
            int ll = tid + 512 * j;
            Ms[ll >> 8][ll & 255] = mvalf(ll & 255, i0 + (ll >> 8));
        }
        __syncthreads();
        #pragma unroll
        for (int ii = 0; ii < 16; ++ii) {
            float bb[4];
            #pragma unroll
            for (int c = 0; c < 4; ++c) bb[c] = Ys[i0 + ii][(tx << 2) + c];
            #pragma unroll
            for (int r = 0; r < 8; ++r) {
                float a = Ms[ii][(ty << 3) + r];
                #pragma unroll
                for (int c = 0; c < 4; ++c) acc[r][c] += a * bb[c];
            }
        }
    }
    #pragma unroll
    for (int r = 0; r < 8; ++r) {
        float4 v = make_float4(acc[r][0], acc[r][1], acc[r][2], acc[r][3]);
        *reinterpret_cast<float4*>(Yb + (size_t)((ty << 3) + r) * N + n0 + (tx << 2)) = v;
    }
}

extern "C" void kernel_launch(void* const* d_in, const int* in_sizes, int n_in,
                              void* d_out, int out_size, void* d_ws, size_t ws_size,
                              hipStream_t stream) {
    const float* X = (const float*)d_in[0];
    float* out = (float*)d_out;
    const int total = in_sizes[0];
    const int Bn = total / (N * N);   // 512
    const size_t needM = (size_t)N * N * 2;   // M bf16 in workspace

    if (ws_size >= needM) {
        unsigned short* Mg = (unsigned short*)d_ws;
        mgen<<<N * N / 256, 256, 0, stream>>>(Mg);
        idct_fused2<<<dim3(Bn * 2), 512, 0, stream>>>(X, Mg, out);
    } else {
        idct_cols<<<dim3(N / 64, N / 64, Bn), 256, 0, stream>>>(X, out);
        idct_rows_inplace<<<dim3(N / 64, Bn), 512, 0, stream>>>(out);
    }
}